// Round 1
// baseline (588.884 us; speedup 1.0000x reference)
//
#include <hip/hip_runtime.h>

// FTScanBasic: inclusive cumsum along axis 0 of xs[8192][4096] fp32.
// d_out layout: [0..4095] = final carry (ys[-1]), [4096..] = ys flat.
//
// Single-pass decoupled-lookback scan (fused; xs read ONCE):
//   tile = (chunk of 64 rows) x (512-float column block), one float2/thread.
//   1. dynamic vid via atomicAdd (dispatch-order-safe, deadlock-free)
//   2. load 64 rows into registers (128 VGPRs), compute column aggregate
//   3. publish aggregate to ws, agent-release flag
//   4. parallel flag-wait (one predecessor flag per thread), agent-acquire
//   5. bulk-sum predecessor aggregates (pipelined, L2/LLC-hot)
//   6. write inclusive rows from registers; last chunk writes carry
// Falls back to the proven two-pass kernel if ws_size < 2 MiB + 8 KiB.

constexpr int T_ROWS = 8192;
constexpr int D_COLS = 4096;
constexpr int THREADS = 256;

// ---------------- fused single-pass geometry ----------------
constexpr int D2       = D_COLS / 2;           // 2048 float2 per row
constexpr int F_CHUNKS = 128;
constexpr int F_RPC    = T_ROWS / F_CHUNKS;    // 64 rows per tile
constexpr int F_NCB    = D2 / THREADS;         // 8 column blocks
constexpr int F_TILES  = F_CHUNKS * F_NCB;     // 1024 tiles

constexpr size_t WS_HDR_WORDS   = 2048;        // 8 KiB header
constexpr int    WS_FLAG_BASE   = 32;          // flags[] start (word idx), ctr at word 0
constexpr size_t WS_AGG_OFF     = WS_HDR_WORDS * 4;
constexpr size_t WS_FUSED_BYTES = WS_AGG_OFF + (size_t)F_TILES * THREADS * sizeof(float2);

__global__ __launch_bounds__(THREADS)
void ws_zero(unsigned* __restrict__ p) {
    p[blockIdx.x * THREADS + threadIdx.x] = 0u;
}

__global__ __launch_bounds__(THREADS, 2)
void scan_fused(const float2* __restrict__ xs,
                float2* __restrict__ ys,
                float2* __restrict__ carry,
                unsigned* __restrict__ wshdr,
                float2* __restrict__ aggv) {
    __shared__ unsigned s_vid;
    if (threadIdx.x == 0) s_vid = atomicAdd(&wshdr[0], 1u);
    __syncthreads();
    const int vid   = (int)s_vid;
    const int chunk = vid / F_NCB;
    const int cb    = vid - chunk * F_NCB;
    const int col2  = cb * THREADS + (int)threadIdx.x;
    const size_t base = (size_t)chunk * F_RPC * D2 + col2;
    unsigned* flags = wshdr + WS_FLAG_BASE;

    // 1) load tile rows into registers (full unroll -> static indices, no scratch)
    float2 v[F_RPC];
#pragma unroll
    for (int r = 0; r < F_RPC; ++r)
        v[r] = xs[base + (size_t)r * D2];

    float2 agg = make_float2(0.f, 0.f);
#pragma unroll
    for (int r = 0; r < F_RPC; ++r) { agg.x += v[r].x; agg.y += v[r].y; }

    // 2) publish aggregate (all threads store, fence, then one release-store flag)
    aggv[(size_t)vid * THREADS + threadIdx.x] = agg;
    __threadfence();
    __syncthreads();
    if (threadIdx.x == 0)
        __hip_atomic_store(&flags[vid], 1u, __ATOMIC_RELEASE, __HIP_MEMORY_SCOPE_AGENT);

    // 3) wait for all same-column predecessor tiles (npred <= 127 < THREADS):
    //    thread t polls the flag of predecessor chunk t.
    const int npred = chunk;
    bool ready = ((int)threadIdx.x >= npred);
    const int pflag = (int)threadIdx.x * F_NCB + cb;
    for (;;) {
        if (__syncthreads_and((int)ready)) break;
        if (!ready) {
            ready = (__hip_atomic_load(&flags[pflag], __ATOMIC_RELAXED,
                                       __HIP_MEMORY_SCOPE_AGENT) != 0u);
            if (!ready) __builtin_amdgcn_s_sleep(2);
        }
    }
    __threadfence();   // acquire: make predecessors' aggv visible (cross-XCD)

    // 4) bulk-sum predecessor aggregates: independent pipelined loads, fixed order
    float2 excl = make_float2(0.f, 0.f);
#pragma unroll 8
    for (int c = 0; c < npred; ++c) {
        float2 a = aggv[(size_t)(c * F_NCB + cb) * THREADS + threadIdx.x];
        excl.x += a.x; excl.y += a.y;
    }

    // 5) inclusive rows straight from registers
    float2 run = excl;
#pragma unroll
    for (int r = 0; r < F_RPC; ++r) {
        run.x += v[r].x; run.y += v[r].y;
        ys[base + (size_t)r * D2] = run;
    }
    if (chunk == F_CHUNKS - 1)
        carry[col2] = run;   // inclusive sum of all T rows
}

// ---------------- fallback: proven two-pass ----------------
constexpr int D4 = D_COLS / 4;
constexpr int CHUNKS = 128;
constexpr int RPC = T_ROWS / CHUNKS;
constexpr int COL_BLOCKS = D4 / THREADS;

__device__ __forceinline__ void acc4(float4& a, const float4& v) {
    a.x += v.x; a.y += v.y; a.z += v.z; a.w += v.w;
}

__global__ __launch_bounds__(THREADS)
void scan_pass1(const float4* __restrict__ xs, float4* __restrict__ partials) {
    const int col4  = blockIdx.x * THREADS + threadIdx.x;
    const int chunk = blockIdx.y;
    const float4* p = xs + (size_t)chunk * RPC * D4 + col4;
    float4 acc = make_float4(0.f, 0.f, 0.f, 0.f);
#pragma unroll 8
    for (int r = 0; r < RPC; ++r) acc4(acc, p[(size_t)r * D4]);
    partials[(size_t)chunk * D4 + col4] = acc;
}

__global__ __launch_bounds__(THREADS)
void scan_pass2(const float4* __restrict__ xs, const float4* __restrict__ partials,
                float4* __restrict__ ys, float4* __restrict__ carry) {
    const int col4  = blockIdx.x * THREADS + threadIdx.x;
    const int chunk = blockIdx.y;
    float4 run = make_float4(0.f, 0.f, 0.f, 0.f);
#pragma unroll 4
    for (int c = 0; c < chunk; ++c) acc4(run, partials[(size_t)c * D4 + col4]);
    const size_t base = (size_t)chunk * RPC * D4 + col4;
#pragma unroll 8
    for (int r = 0; r < RPC; ++r) {
        acc4(run, xs[base + (size_t)r * D4]);
        ys[base + (size_t)r * D4] = run;
    }
    if (chunk == CHUNKS - 1) carry[col4] = run;
}

extern "C" void kernel_launch(void* const* d_in, const int* in_sizes, int n_in,
                              void* d_out, int out_size, void* d_ws, size_t ws_size,
                              hipStream_t stream) {
    float* out = (float*)d_out;
    if (ws_size >= WS_FUSED_BYTES) {
        unsigned* wshdr = (unsigned*)d_ws;
        float2*   aggv  = (float2*)((char*)d_ws + WS_AGG_OFF);
        ws_zero<<<dim3((unsigned)(WS_HDR_WORDS / THREADS)), dim3(THREADS), 0, stream>>>(wshdr);
        scan_fused<<<dim3(F_TILES), dim3(THREADS), 0, stream>>>(
            (const float2*)d_in[0],
            (float2*)(out + D_COLS),   // ys
            (float2*)out,              // carry
            wshdr, aggv);
    } else {
        const float4* xs = (const float4*)d_in[0];
        float4* carry = (float4*)out;
        float4* ys = (float4*)(out + D_COLS);
        float4* partials = (float4*)d_ws;
        dim3 grid(COL_BLOCKS, CHUNKS);
        scan_pass1<<<grid, THREADS, 0, stream>>>(xs, partials);
        scan_pass2<<<grid, THREADS, 0, stream>>>(xs, partials, ys, carry);
    }
}

// Round 3
// 245.289 us; speedup vs baseline: 2.4008x; 2.4008x over previous
//
#include <hip/hip_runtime.h>

// FTScanBasic: inclusive cumsum along axis 0 of xs[8192][4096] fp32.
// d_out layout: [0..4095] = final carry (ys[-1]), [4096..] = ys flat.
//
// Two-pass chunked scan (proven structure; round-1 lookback fusion regressed
// 5x due to agent-scope fence L2-writeback storms — reverted).
//   pass1: per-chunk column sums -> partials[CHUNKS][D4] (float4) in d_ws.
//          Side effect: parks all of xs (134 MB) in the 256 MiB LLC.
//   pass2: each block sums its <chunk predecessor partial rows (coalesced,
//          independent, L2/LLC-hot), then streams its chunk: run += x,
//          write inclusive row. Chunk 127 writes carry.
// ys/carry stores are NONTEMPORAL — they stream past the LLC so the 134 MB
// of ys writes do not evict the xs lines pass2 is re-reading (134 xs +
// 134 ys > 256 MiB LLC; nt-writes remove the contention).
// NOTE: __builtin_nontemporal_store requires a native clang vector type,
// not HIP_vector_type — hence f32x4 ext_vector for the store path.

constexpr int T_ROWS = 8192;
constexpr int D_COLS = 4096;
constexpr int D4 = D_COLS / 4;          // 1024 float4 per row
constexpr int CHUNKS = 128;
constexpr int RPC = T_ROWS / CHUNKS;    // 64 rows per chunk
constexpr int THREADS = 256;
constexpr int COL_BLOCKS = D4 / THREADS; // 4

typedef float f32x4 __attribute__((ext_vector_type(4)));

__device__ __forceinline__ void acc4(float4& a, const float4& v) {
    a.x += v.x; a.y += v.y; a.z += v.z; a.w += v.w;
}

__device__ __forceinline__ void nt_store4(const float4& v, float4* p) {
    f32x4 w; w.x = v.x; w.y = v.y; w.z = v.z; w.w = v.w;
    __builtin_nontemporal_store(w, reinterpret_cast<f32x4*>(p));
}

__global__ __launch_bounds__(THREADS)
void scan_pass1(const float4* __restrict__ xs, float4* __restrict__ partials) {
    const int col4  = blockIdx.x * THREADS + threadIdx.x;  // 0..1023
    const int chunk = blockIdx.y;
    const float4* p = xs + (size_t)chunk * RPC * D4 + col4;
    float4 acc = make_float4(0.f, 0.f, 0.f, 0.f);
#pragma unroll 8
    for (int r = 0; r < RPC; ++r) {
        acc4(acc, p[(size_t)r * D4]);
    }
    partials[(size_t)chunk * D4 + col4] = acc;   // cacheable: re-read in pass2
}

__global__ __launch_bounds__(THREADS)
void scan_pass2(const float4* __restrict__ xs, const float4* __restrict__ partials,
                float4* __restrict__ ys, float4* __restrict__ carry) {
    const int col4  = blockIdx.x * THREADS + threadIdx.x;
    const int chunk = blockIdx.y;

    // Exclusive prefix for this chunk: sum predecessor partial rows directly.
    // <=127 independent coalesced loads from L2/LLC; pipelined by unroll.
    float4 run = make_float4(0.f, 0.f, 0.f, 0.f);
#pragma unroll 4
    for (int c = 0; c < chunk; ++c) {
        acc4(run, partials[(size_t)c * D4 + col4]);
    }

    // Stream this chunk: inclusive scan. xs reads are LLC-hot (parked by
    // pass1); ys writes are nontemporal so they don't evict xs from LLC.
    const size_t base = (size_t)chunk * RPC * D4 + col4;
#pragma unroll 8
    for (int r = 0; r < RPC; ++r) {
        acc4(run, xs[base + (size_t)r * D4]);
        nt_store4(run, &ys[base + (size_t)r * D4]);
    }

    if (chunk == CHUNKS - 1) {
        nt_store4(run, &carry[col4]);  // ys[-1]
    }
}

extern "C" void kernel_launch(void* const* d_in, const int* in_sizes, int n_in,
                              void* d_out, int out_size, void* d_ws, size_t ws_size,
                              hipStream_t stream) {
    const float4* xs = (const float4*)d_in[0];
    float* out = (float*)d_out;
    float4* carry = (float4*)out;                 // first 4096 floats
    float4* ys = (float4*)(out + D_COLS);         // 16 KiB offset, 16B-aligned
    float4* partials = (float4*)d_ws;             // CHUNKS * D4 * 16 B = 2 MiB

    dim3 grid(COL_BLOCKS, CHUNKS);                // 4 x 128 = 512 blocks
    scan_pass1<<<grid, THREADS, 0, stream>>>(xs, partials);
    scan_pass2<<<grid, THREADS, 0, stream>>>(xs, partials, ys, carry);
}